// Round 3
// baseline (975.540 us; speedup 1.0000x reference)
//
#include <hip/hip_runtime.h>

#define N_NODES 100000
#define NPAD    100096   // 782 * 128
#define E_EDGES 800000

typedef _Float16 f16;
typedef _Float16 f16x4 __attribute__((ext_vector_type(4)));
typedef _Float16 f16x8 __attribute__((ext_vector_type(8)));
typedef float    f32x4 __attribute__((ext_vector_type(4)));

__device__ inline void async16(const void* g, void* l) {
    __builtin_amdgcn_global_load_lds(
        (const __attribute__((address_space(1))) void*)g,
        (__attribute__((address_space(3))) void*)l, 16, 0, 0);
}

// ---------------- graph build ----------------
__global__ void k_deg(const int* __restrict__ ei, int* __restrict__ deg) {
    int e = blockIdx.x * 256 + threadIdx.x;
    if (e < E_EDGES) atomicAdd(&deg[ei[e]], 1);
}

// scan part 1 + dinv fused (reads deg anyway)
__global__ void k_scan1(const int* __restrict__ deg, int* __restrict__ off,
                        int* __restrict__ bsum, float* __restrict__ dinv) {
    __shared__ int s[256];
    int i = blockIdx.x * 256 + threadIdx.x;
    int v = (i < N_NODES) ? deg[i] : 0;
    if (i < N_NODES) dinv[i] = rsqrtf((float)(v + 1));  // +1 self loop
    s[threadIdx.x] = v;
    __syncthreads();
    for (int d = 1; d < 256; d <<= 1) {
        int t = (threadIdx.x >= d) ? s[threadIdx.x - d] : 0;
        __syncthreads();
        s[threadIdx.x] += t;
        __syncthreads();
    }
    if (i < N_NODES) off[i] = s[threadIdx.x] - v;   // exclusive
    if (threadIdx.x == 255) bsum[blockIdx.x] = s[255];
}

__global__ void k_scan2(int* __restrict__ bsum, int nb) {
    __shared__ int s[512];
    int tid = threadIdx.x;
    int v = (tid < nb) ? bsum[tid] : 0;
    s[tid] = v;
    __syncthreads();
    for (int d = 1; d < 512; d <<= 1) {
        int t = (tid >= d) ? s[tid - d] : 0;
        __syncthreads();
        s[tid] += t;
        __syncthreads();
    }
    if (tid < nb) bsum[tid] = s[tid] - v;           // exclusive base per block
}

__global__ void k_scan3(int* __restrict__ off, const int* __restrict__ bsum) {
    int i = blockIdx.x * 256 + threadIdx.x;
    if (i < N_NODES) off[i] += bsum[blockIdx.x];
    if (i == 0) off[N_NODES] = E_EDGES;
}

__global__ void k_fill(const int* __restrict__ ei, const int* __restrict__ off,
                       int* __restrict__ cursor, int* __restrict__ csr) {
    int e = blockIdx.x * 256 + threadIdx.x;
    if (e >= E_EDGES) return;
    int dst = ei[e];
    int src = ei[E_EDGES + e];
    int pos = atomicAdd(&cursor[dst], 1);
    csr[off[dst] + pos] = src;
}

// ---------------- conversions ----------------
__global__ void k_x_to_f16(const float* __restrict__ x, f16* __restrict__ xh) {
    int i = blockIdx.x * 256 + threadIdx.x;             // 4 floats / thread
    if (i >= (N_NODES * 256) / 4) return;
    float4 v = ((const float4*)x)[i];
    f16x4 o;
    o.x = (f16)v.x; o.y = (f16)v.y; o.z = (f16)v.z; o.w = (f16)v.w;
    ((f16x4*)xh)[i] = o;
}

// W[K][M] fp32 -> Wt[M][K] f16
__global__ void k_transpose(const float* __restrict__ W, f16* __restrict__ Wt,
                            int K, int M) {
    int m = blockIdx.x * 256 + threadIdx.x;
    int k = blockIdx.y;
    if (m < M) Wt[(size_t)m * K + k] = (f16)W[(size_t)k * M + m];
}

// ---------------- GEMM: C[NPAD x M] = A[NPAD x K] * Bt[M x K]^T ----------------
// Tile 128x256, 4 waves, wave-tile 64x128. Halves/eliminates A re-reads vs 128x128.
// MODE: 0 = raw f16 out, 1 = bias+relu f16 out, 2 = bias f32 out
template<int K, int M, int MODE>
__launch_bounds__(256, 2)
__global__ void k_gemm(const f16* __restrict__ A, const f16* __restrict__ B,
                       void* __restrict__ C, const float* __restrict__ bias) {
    __shared__ f16 As[128 * 32];   //  8 KB
    __shared__ f16 Bs[256 * 32];   // 16 KB
    int tid  = threadIdx.x;
    int wave = tid >> 6, lane = tid & 63;
    int wr = (wave >> 1) * 64, wc = (wave & 1) * 128;
    int lm = lane & 15, q = lane >> 4;
    int rowBase = blockIdx.x * 128;
    int colBase = blockIdx.y * 256;

    f32x4 acc[4][8] = {};
    const f16* Ag = A + (size_t)rowBase * K;
    const f16* Bg = B + (size_t)colBase * K;

    for (int kt = 0; kt < K; kt += 32) {
        __syncthreads();
        {   // As: 512 16B-chunks, Bs: 1024 chunks; chunk c: row=c>>2, seg=c&3
            int c0 = tid, c1 = tid + 256;
            async16(Ag + (size_t)(c0 >> 2) * K + kt + (c0 & 3) * 8, &As[c0 * 8]);
            async16(Ag + (size_t)(c1 >> 2) * K + kt + (c1 & 3) * 8, &As[c1 * 8]);
#pragma unroll
            for (int r = 0; r < 4; ++r) {
                int c = tid + r * 256;
                async16(Bg + (size_t)(c >> 2) * K + kt + (c & 3) * 8, &Bs[c * 8]);
            }
        }
        __syncthreads();

        f16x8 a[4], b[8];
#pragma unroll
        for (int i = 0; i < 4; ++i)
            a[i] = *(const f16x8*)&As[(wr + i * 16 + lm) * 32 + q * 8];
#pragma unroll
        for (int j = 0; j < 8; ++j)
            b[j] = *(const f16x8*)&Bs[(wc + j * 16 + lm) * 32 + q * 8];
#pragma unroll
        for (int i = 0; i < 4; ++i)
#pragma unroll
            for (int j = 0; j < 8; ++j)
                acc[i][j] = __builtin_amdgcn_mfma_f32_16x16x32_f16(
                    a[i], b[j], acc[i][j], 0, 0, 0);
    }

#pragma unroll
    for (int i = 0; i < 4; ++i) {
        int gr0 = rowBase + wr + i * 16 + q * 4;
#pragma unroll
        for (int j = 0; j < 8; ++j) {
            int gc = colBase + wc + j * 16 + lm;
#pragma unroll
            for (int r = 0; r < 4; ++r) {
                int gr = gr0 + r;
                if (gr < N_NODES) {
                    float v = acc[i][j][r];
                    if (MODE == 2) {
                        ((float*)C)[(size_t)gr * M + gc] = v + bias[gc];
                    } else if (MODE == 1) {
                        float rr = v + bias[gc];
                        ((f16*)C)[(size_t)gr * M + gc] = (f16)(rr > 0.f ? rr : 0.f);
                    } else {
                        ((f16*)C)[(size_t)gr * M + gc] = (f16)v;
                    }
                }
            }
        }
    }
}

// ---------------- aggregation ----------------
// out_i = dinv_i * (dinv_i*t_i + sum_j dinv_j*t_j)  [+bias, relu if ACT]
template<int VE> struct VecT;
template<> struct VecT<4> { typedef f16x4 type; };
template<> struct VecT<8> { typedef f16x8 type; };

template<int CH, bool ACT>
__global__ void k_agg(const f16* __restrict__ t, const int* __restrict__ off,
                      const int* __restrict__ csr, const float* __restrict__ dinv,
                      const float* __restrict__ bias, f16* __restrict__ h) {
    constexpr int VE = CH / 64;
    typedef typename VecT<VE>::type vec;
    int node = blockIdx.x * 4 + (threadIdx.x >> 6);
    if (node >= N_NODES) return;
    int lane = threadIdx.x & 63;
    float di = dinv[node];

    const vec* rows = (const vec*)t;
    vec v = rows[(size_t)node * 64 + lane];
    float acc[VE];
#pragma unroll
    for (int j = 0; j < VE; ++j) acc[j] = di * (float)v[j];

    int s = off[node], e = off[node + 1];
    int idx = s;
    for (; idx + 4 <= e; idx += 4) {
        int i0 = csr[idx], i1 = csr[idx + 1], i2 = csr[idx + 2], i3 = csr[idx + 3];
        vec u0 = rows[(size_t)i0 * 64 + lane];
        vec u1 = rows[(size_t)i1 * 64 + lane];
        vec u2 = rows[(size_t)i2 * 64 + lane];
        vec u3 = rows[(size_t)i3 * 64 + lane];
        float d0 = dinv[i0], d1 = dinv[i1], d2 = dinv[i2], d3 = dinv[i3];
#pragma unroll
        for (int j = 0; j < VE; ++j)
            acc[j] += d0 * (float)u0[j] + d1 * (float)u1[j]
                    + d2 * (float)u2[j] + d3 * (float)u3[j];
    }
    for (; idx < e; ++idx) {
        int src = csr[idx];
        float dj = dinv[src];
        vec u = rows[(size_t)src * 64 + lane];
#pragma unroll
        for (int j = 0; j < VE; ++j) acc[j] += dj * (float)u[j];
    }

    vec o;
#pragma unroll
    for (int j = 0; j < VE; ++j) {
        float r = di * acc[j];
        if (ACT) {
            r += bias[lane * VE + j];
            r = r > 0.f ? r : 0.f;
        }
        o[j] = (f16)r;
    }
    ((vec*)h)[(size_t)node * 64 + lane] = o;
}

// ---------------- launch ----------------
extern "C" void kernel_launch(void* const* d_in, const int* in_sizes, int n_in,
                              void* d_out, int out_size, void* d_ws, size_t ws_size,
                              hipStream_t stream) {
    const float* x   = (const float*)d_in[0];
    const int*   ei  = (const int*)d_in[1];
    const float* W1  = (const float*)d_in[2];
    const float* b1  = (const float*)d_in[3];
    const float* W2  = (const float*)d_in[4];
    const float* b2  = (const float*)d_in[5];
    const float* W3  = (const float*)d_in[6];
    const float* b3  = (const float*)d_in[7];
    const float* Wfc = (const float*)d_in[8];
    const float* bfc = (const float*)d_in[9];

    char* wsb = (char*)d_ws;
    size_t o = 0;
    auto alloc = [&](size_t bytes) -> void* {
        void* p = wsb + o;
        o += (bytes + 255) & ~(size_t)255;
        return p;
    };

    f16* xh   = (f16*)alloc((size_t)NPAD * 256 * 2);
    f16* t    = (f16*)alloc((size_t)NPAD * 512 * 2);
    f16* h    = (f16*)alloc((size_t)NPAD * 512 * 2);
    f16* Wt1  = (f16*)alloc(512 * 256 * 2);
    f16* Wt2  = (f16*)alloc(512 * 512 * 2);
    f16* Wt3  = (f16*)alloc(512 * 512 * 2);
    f16* Wtfc = (f16*)alloc(256 * 512 * 2);
    int* deg    = (int*)alloc(N_NODES * 4);
    float* dinv = (float*)alloc(N_NODES * 4);
    int* off    = (int*)alloc((N_NODES + 1) * 4);
    int* cursor = (int*)alloc(N_NODES * 4);
    int* bsum   = (int*)alloc(4096 * 4);
    int* csr    = (int*)alloc((size_t)E_EDGES * 4);

    f16* a1 = t;   // layer-1 agg output [NPAD x 256] aliases t (free until gemm2)

    const int NB = (N_NODES + 255) / 256;   // 391

    hipMemsetAsync(deg, 0, N_NODES * 4, stream);
    hipMemsetAsync(cursor, 0, N_NODES * 4, stream);

    k_deg<<<(E_EDGES + 255) / 256, 256, 0, stream>>>(ei, deg);
    k_scan1<<<NB, 256, 0, stream>>>(deg, off, bsum, dinv);
    k_scan2<<<1, 512, 0, stream>>>(bsum, NB);
    k_scan3<<<NB, 256, 0, stream>>>(off, bsum);
    k_fill<<<(E_EDGES + 255) / 256, 256, 0, stream>>>(ei, off, cursor, csr);

    k_x_to_f16<<<(N_NODES * 256 / 4 + 255) / 256, 256, 0, stream>>>(x, xh);
    k_transpose<<<dim3(2, 256), 256, 0, stream>>>(W1, Wt1, 256, 512);
    k_transpose<<<dim3(2, 512), 256, 0, stream>>>(W2, Wt2, 512, 512);
    k_transpose<<<dim3(2, 512), 256, 0, stream>>>(W3, Wt3, 512, 512);
    k_transpose<<<dim3(1, 512), 256, 0, stream>>>(Wfc, Wtfc, 512, 256);

    dim3 g2(NPAD / 128, 2), g1(NPAD / 128, 1);
    const int AGG_GRID = N_NODES / 4;   // 25000

    // layer 1 reordered: agg(X) @ W1  (agg on 256-dim input = half the gather)
    k_agg<256, false><<<AGG_GRID, 256, 0, stream>>>(xh, off, csr, dinv, nullptr, a1);
    k_gemm<256, 512, 1><<<g2, 256, 0, stream>>>(a1, Wt1, h, b1);
    // layers 2,3: gemm then agg (bias+relu fused in agg)
    k_gemm<512, 512, 0><<<g2, 256, 0, stream>>>(h, Wt2, t, nullptr);
    k_agg<512, true><<<AGG_GRID, 256, 0, stream>>>(t, off, csr, dinv, b2, h);
    k_gemm<512, 512, 0><<<g2, 256, 0, stream>>>(h, Wt3, t, nullptr);
    k_agg<512, true><<<AGG_GRID, 256, 0, stream>>>(t, off, csr, dinv, b3, h);
    // final FC
    k_gemm<512, 256, 2><<<g1, 256, 0, stream>>>(h, Wtfc, d_out, bfc);
}

// Round 4
// 922.317 us; speedup vs baseline: 1.0577x; 1.0577x over previous
//
#include <hip/hip_runtime.h>

#define N_NODES 100000
#define NPAD    100096   // 782 * 128
#define E_EDGES 800000
#define HALF_STRIDE ((size_t)NPAD * 256)

typedef _Float16 f16;
typedef _Float16 f16x4 __attribute__((ext_vector_type(4)));
typedef _Float16 f16x8 __attribute__((ext_vector_type(8)));
typedef float    f32x4 __attribute__((ext_vector_type(4)));

__device__ inline void async16(const void* g, void* l) {
    __builtin_amdgcn_global_load_lds(
        (const __attribute__((address_space(1))) void*)g,
        (__attribute__((address_space(3))) void*)l, 16, 0, 0);
}

// ---------------- graph build ----------------
__global__ void k_deg(const int* __restrict__ ei, int* __restrict__ deg) {
    int e = blockIdx.x * 256 + threadIdx.x;
    if (e < E_EDGES) atomicAdd(&deg[ei[e]], 1);
}

__global__ void k_scan1(const int* __restrict__ deg, int* __restrict__ off,
                        int* __restrict__ bsum, float* __restrict__ dinv) {
    __shared__ int s[256];
    int i = blockIdx.x * 256 + threadIdx.x;
    int v = (i < N_NODES) ? deg[i] : 0;
    if (i < N_NODES) dinv[i] = rsqrtf((float)(v + 1));  // +1 self loop
    s[threadIdx.x] = v;
    __syncthreads();
    for (int d = 1; d < 256; d <<= 1) {
        int t = (threadIdx.x >= d) ? s[threadIdx.x - d] : 0;
        __syncthreads();
        s[threadIdx.x] += t;
        __syncthreads();
    }
    if (i < N_NODES) off[i] = s[threadIdx.x] - v;   // exclusive
    if (threadIdx.x == 255) bsum[blockIdx.x] = s[255];
}

__global__ void k_scan2(int* __restrict__ bsum, int nb) {
    __shared__ int s[512];
    int tid = threadIdx.x;
    int v = (tid < nb) ? bsum[tid] : 0;
    s[tid] = v;
    __syncthreads();
    for (int d = 1; d < 512; d <<= 1) {
        int t = (tid >= d) ? s[tid - d] : 0;
        __syncthreads();
        s[tid] += t;
        __syncthreads();
    }
    if (tid < nb) bsum[tid] = s[tid] - v;
}

__global__ void k_scan3(int* __restrict__ off, const int* __restrict__ bsum) {
    int i = blockIdx.x * 256 + threadIdx.x;
    if (i < N_NODES) off[i] += bsum[blockIdx.x];
    if (i == 0) off[N_NODES] = E_EDGES;
}

__global__ void k_fill(const int* __restrict__ ei, const int* __restrict__ off,
                       int* __restrict__ cursor, int* __restrict__ csr) {
    int e = blockIdx.x * 256 + threadIdx.x;
    if (e >= E_EDGES) return;
    int dst = ei[e];
    int src = ei[E_EDGES + e];
    int pos = atomicAdd(&cursor[dst], 1);
    csr[off[dst] + pos] = src;
}

// ---------------- conversions ----------------
__global__ void k_x_to_f16(const float* __restrict__ x, f16* __restrict__ xh) {
    int i = blockIdx.x * 256 + threadIdx.x;
    if (i >= (N_NODES * 256) / 4) return;
    float4 v = ((const float4*)x)[i];
    f16x4 o;
    o.x = (f16)v.x; o.y = (f16)v.y; o.z = (f16)v.z; o.w = (f16)v.w;
    ((f16x4*)xh)[i] = o;
}

__global__ void k_transpose(const float* __restrict__ W, f16* __restrict__ Wt,
                            int K, int M) {
    int m = blockIdx.x * 256 + threadIdx.x;
    int k = blockIdx.y;
    if (m < M) Wt[(size_t)m * K + k] = (f16)W[(size_t)k * M + m];
}

// ---------------- GEMM: C[NPAD x M] = A[NPAD x K] * Bt[M x K]^T ----------------
// 128x128 tile, 4 waves (2x2), wave-tile 64x64, BK=32 (m97 structure).
// MODE: 0 = raw f16 out, 1 = bias+relu f16 out, 2 = bias f32 out (guarded scalar)
// SPLIT: f16 output goes to two [NPAD x 256] half-tensors (col>>8 selects half)
template<int K, int M, int MODE, bool SPLIT>
__launch_bounds__(256, 2)
__global__ void k_gemm(const f16* __restrict__ A, const f16* __restrict__ B,
                       void* __restrict__ C, const float* __restrict__ bias) {
    __shared__ __align__(16) char smem[16384];
    f16* As = (f16*)smem;             // 128*32 = 8 KB
    f16* Bs = (f16*)(smem + 8192);    // 128*32 = 8 KB
    int tid  = threadIdx.x;
    int wave = tid >> 6, lane = tid & 63;
    int wr = (wave >> 1) * 64, wc = (wave & 1) * 64;
    int lm = lane & 15, q = lane >> 4;
    int rowBase = blockIdx.x * 128;
    int colBase = blockIdx.y * 128;

    f32x4 acc[4][4] = {};
    const f16* Ag = A + (size_t)rowBase * K;
    const f16* Bg = B + (size_t)colBase * K;

    int c0 = tid, c1 = tid + 256;   // 16B chunk ids: row = c>>2, seg = c&3
    for (int kt = 0; kt < K; kt += 32) {
        __syncthreads();
        async16(Ag + (size_t)(c0 >> 2) * K + kt + (c0 & 3) * 8, &As[c0 * 8]);
        async16(Ag + (size_t)(c1 >> 2) * K + kt + (c1 & 3) * 8, &As[c1 * 8]);
        async16(Bg + (size_t)(c0 >> 2) * K + kt + (c0 & 3) * 8, &Bs[c0 * 8]);
        async16(Bg + (size_t)(c1 >> 2) * K + kt + (c1 & 3) * 8, &Bs[c1 * 8]);
        __syncthreads();

        f16x8 a[4], b[4];
#pragma unroll
        for (int i = 0; i < 4; ++i) {
            a[i] = *(const f16x8*)&As[(wr + i * 16 + lm) * 32 + q * 8];
            b[i] = *(const f16x8*)&Bs[(wc + i * 16 + lm) * 32 + q * 8];
        }
#pragma unroll
        for (int i = 0; i < 4; ++i)
#pragma unroll
            for (int j = 0; j < 4; ++j)
                acc[i][j] = __builtin_amdgcn_mfma_f32_16x16x32_f16(
                    a[i], b[j], acc[i][j], 0, 0, 0);
    }

    if (MODE == 2) {
        // fp32 output (final FC) — guarded scalar stores
#pragma unroll
        for (int i = 0; i < 4; ++i) {
            int gr0 = rowBase + wr + i * 16 + q * 4;
#pragma unroll
            for (int j = 0; j < 4; ++j) {
                int gc = colBase + wc + j * 16 + lm;
                float bj = bias[gc];
#pragma unroll
                for (int r = 0; r < 4; ++r) {
                    int gr = gr0 + r;
                    if (gr < N_NODES)
                        ((float*)C)[(size_t)gr * M + gc] = acc[i][j][r] + bj;
                }
            }
        }
    } else {
        // f16 output: LDS transpose -> f16x8 (dwordx4) stores, no guards
        __syncthreads();
        f16* Ep = (f16*)smem + wave * (16 * 80);   // 2560 B/wave, stride 80 f16
#pragma unroll
        for (int i = 0; i < 4; ++i) {
#pragma unroll
            for (int j = 0; j < 4; ++j) {
                int colg = colBase + wc + j * 16 + lm;
#pragma unroll
                for (int r = 0; r < 4; ++r) {
                    float v = acc[i][j][r];
                    if (MODE == 1) {
                        v += bias[colg];
                        v = v > 0.f ? v : 0.f;
                    }
                    Ep[(q * 4 + r) * 80 + j * 16 + lm] = (f16)v;
                }
            }
            __syncthreads();
            int row0 = lane >> 3, c8 = lane & 7;
            f16x8 v0 = *(const f16x8*)&Ep[row0 * 80 + c8 * 8];
            f16x8 v1 = *(const f16x8*)&Ep[(row0 + 8) * 80 + c8 * 8];
            int gr0 = rowBase + wr + i * 16 + row0;
            int gc  = colBase + wc + c8 * 8;
            if (SPLIT) {
                f16* base = (f16*)C + (size_t)(gc >> 8) * HALF_STRIDE;
                int cl = gc & 255;
                *(f16x8*)&base[(size_t)gr0 * 256 + cl] = v0;
                *(f16x8*)&base[(size_t)(gr0 + 8) * 256 + cl] = v1;
            } else {
                *(f16x8*)&((f16*)C)[(size_t)gr0 * M + gc] = v0;
                *(f16x8*)&((f16*)C)[(size_t)(gr0 + 8) * M + gc] = v1;
            }
            __syncthreads();
        }
    }
}

// ---------------- aggregation (contiguous, CH channels) ----------------
template<int VE> struct VecT;
template<> struct VecT<4> { typedef f16x4 type; };
template<> struct VecT<8> { typedef f16x8 type; };

template<int CH, bool ACT>
__global__ void k_agg(const f16* __restrict__ t, const int* __restrict__ off,
                      const int* __restrict__ csr, const float* __restrict__ dinv,
                      const float* __restrict__ bias, f16* __restrict__ h) {
    constexpr int VE = CH / 64;
    typedef typename VecT<VE>::type vec;
    int node = blockIdx.x * 4 + (threadIdx.x >> 6);
    if (node >= N_NODES) return;
    int lane = threadIdx.x & 63;
    float di = dinv[node];

    const vec* rows = (const vec*)t;
    vec v = rows[(size_t)node * 64 + lane];
    float acc[VE];
#pragma unroll
    for (int j = 0; j < VE; ++j) acc[j] = di * (float)v[j];

    int s = off[node], e = off[node + 1];
    int idx = s;
    for (; idx + 4 <= e; idx += 4) {
        int i0 = csr[idx], i1 = csr[idx + 1], i2 = csr[idx + 2], i3 = csr[idx + 3];
        vec u0 = rows[(size_t)i0 * 64 + lane];
        vec u1 = rows[(size_t)i1 * 64 + lane];
        vec u2 = rows[(size_t)i2 * 64 + lane];
        vec u3 = rows[(size_t)i3 * 64 + lane];
        float d0 = dinv[i0], d1 = dinv[i1], d2 = dinv[i2], d3 = dinv[i3];
#pragma unroll
        for (int j = 0; j < VE; ++j)
            acc[j] += d0 * (float)u0[j] + d1 * (float)u1[j]
                    + d2 * (float)u2[j] + d3 * (float)u3[j];
    }
    for (; idx < e; ++idx) {
        int src = csr[idx];
        float dj = dinv[src];
        vec u = rows[(size_t)src * 64 + lane];
#pragma unroll
        for (int j = 0; j < VE; ++j) acc[j] += dj * (float)u[j];
    }

    vec o;
#pragma unroll
    for (int j = 0; j < VE; ++j) {
        float r = di * acc[j];
        if (ACT) {
            r += bias[lane * VE + j];
            r = r > 0.f ? r : 0.f;
        }
        o[j] = (f16)r;
    }
    ((vec*)h)[(size_t)node * 64 + lane] = o;
}

// ---------------- aggregation on split-half t (256 ch per half) ----------------
// t: two [NPAD x 256] halves; h: contiguous [NPAD x 512]
template<bool ACT>
__global__ void k_agg_split(const f16* __restrict__ t, const int* __restrict__ off,
                            const int* __restrict__ csr, const float* __restrict__ dinv,
                            const float* __restrict__ bias, f16* __restrict__ h) {
    int node = blockIdx.x * 4 + (threadIdx.x >> 6);
    if (node >= N_NODES) return;
    int half = blockIdx.y;
    int lane = threadIdx.x & 63;
    float di = dinv[node];

    const f16x4* rows = (const f16x4*)(t + (size_t)half * HALF_STRIDE);
    f16x4 v = rows[(size_t)node * 64 + lane];
    float acc[4];
#pragma unroll
    for (int j = 0; j < 4; ++j) acc[j] = di * (float)v[j];

    int s = off[node], e = off[node + 1];
    int idx = s;
    for (; idx + 4 <= e; idx += 4) {
        int i0 = csr[idx], i1 = csr[idx + 1], i2 = csr[idx + 2], i3 = csr[idx + 3];
        f16x4 u0 = rows[(size_t)i0 * 64 + lane];
        f16x4 u1 = rows[(size_t)i1 * 64 + lane];
        f16x4 u2 = rows[(size_t)i2 * 64 + lane];
        f16x4 u3 = rows[(size_t)i3 * 64 + lane];
        float d0 = dinv[i0], d1 = dinv[i1], d2 = dinv[i2], d3 = dinv[i3];
#pragma unroll
        for (int j = 0; j < 4; ++j)
            acc[j] += d0 * (float)u0[j] + d1 * (float)u1[j]
                    + d2 * (float)u2[j] + d3 * (float)u3[j];
    }
    for (; idx < e; ++idx) {
        int src = csr[idx];
        float dj = dinv[src];
        f16x4 u = rows[(size_t)src * 64 + lane];
#pragma unroll
        for (int j = 0; j < 4; ++j) acc[j] += dj * (float)u[j];
    }

    f16x4 o;
#pragma unroll
    for (int j = 0; j < 4; ++j) {
        float r = di * acc[j];
        if (ACT) {
            r += bias[half * 256 + lane * 4 + j];
            r = r > 0.f ? r : 0.f;
        }
        o[j] = (f16)r;
    }
    *(f16x4*)&h[(size_t)node * 512 + half * 256 + lane * 4] = o;
}

// ---------------- launch ----------------
extern "C" void kernel_launch(void* const* d_in, const int* in_sizes, int n_in,
                              void* d_out, int out_size, void* d_ws, size_t ws_size,
                              hipStream_t stream) {
    const float* x   = (const float*)d_in[0];
    const int*   ei  = (const int*)d_in[1];
    const float* W1  = (const float*)d_in[2];
    const float* b1  = (const float*)d_in[3];
    const float* W2  = (const float*)d_in[4];
    const float* b2  = (const float*)d_in[5];
    const float* W3  = (const float*)d_in[6];
    const float* b3  = (const float*)d_in[7];
    const float* Wfc = (const float*)d_in[8];
    const float* bfc = (const float*)d_in[9];

    char* wsb = (char*)d_ws;
    size_t o = 0;
    auto alloc = [&](size_t bytes) -> void* {
        void* p = wsb + o;
        o += (bytes + 255) & ~(size_t)255;
        return p;
    };

    f16* xh   = (f16*)alloc((size_t)NPAD * 256 * 2);
    f16* t    = (f16*)alloc((size_t)NPAD * 512 * 2);   // split: 2 x [NPAD x 256]
    f16* h    = (f16*)alloc((size_t)NPAD * 512 * 2);   // contiguous [NPAD x 512]
    f16* Wt1  = (f16*)alloc(512 * 256 * 2);
    f16* Wt2  = (f16*)alloc(512 * 512 * 2);
    f16* Wt3  = (f16*)alloc(512 * 512 * 2);
    f16* Wtfc = (f16*)alloc(256 * 512 * 2);
    int* deg    = (int*)alloc(N_NODES * 4);
    float* dinv = (float*)alloc(N_NODES * 4);
    int* off    = (int*)alloc((N_NODES + 1) * 4);
    int* cursor = (int*)alloc(N_NODES * 4);
    int* bsum   = (int*)alloc(4096 * 4);
    int* csr    = (int*)alloc((size_t)E_EDGES * 4);

    f16* a1 = t;   // layer-1 agg output [NPAD x 256] aliases t (free until gemm2)

    const int NB = (N_NODES + 255) / 256;   // 391

    hipMemsetAsync(deg, 0, N_NODES * 4, stream);
    hipMemsetAsync(cursor, 0, N_NODES * 4, stream);

    k_deg<<<(E_EDGES + 255) / 256, 256, 0, stream>>>(ei, deg);
    k_scan1<<<NB, 256, 0, stream>>>(deg, off, bsum, dinv);
    k_scan2<<<1, 512, 0, stream>>>(bsum, NB);
    k_scan3<<<NB, 256, 0, stream>>>(off, bsum);
    k_fill<<<(E_EDGES + 255) / 256, 256, 0, stream>>>(ei, off, cursor, csr);

    k_x_to_f16<<<(N_NODES * 256 / 4 + 255) / 256, 256, 0, stream>>>(x, xh);
    k_transpose<<<dim3(2, 256), 256, 0, stream>>>(W1, Wt1, 256, 512);
    k_transpose<<<dim3(2, 512), 256, 0, stream>>>(W2, Wt2, 512, 512);
    k_transpose<<<dim3(2, 512), 256, 0, stream>>>(W3, Wt3, 512, 512);
    k_transpose<<<dim3(1, 512), 256, 0, stream>>>(Wfc, Wtfc, 512, 256);

    dim3 g4(NPAD / 128, 4), g2(NPAD / 128, 2);
    const int AGG_GRID = N_NODES / 4;   // 25000
    dim3 gs(AGG_GRID, 2);

    // layer 1: agg(X) @ W1 (+bias+relu in gemm epilogue)
    k_agg<256, false><<<AGG_GRID, 256, 0, stream>>>(xh, off, csr, dinv, nullptr, a1);
    k_gemm<256, 512, 1, false><<<g4, 256, 0, stream>>>(a1, Wt1, h, b1);
    // layers 2,3: gemm (split-half out) then agg per half (bias+relu fused)
    k_gemm<512, 512, 0, true><<<g4, 256, 0, stream>>>(h, Wt2, t, nullptr);
    k_agg_split<true><<<gs, 256, 0, stream>>>(t, off, csr, dinv, b2, h);
    k_gemm<512, 512, 0, true><<<g4, 256, 0, stream>>>(h, Wt3, t, nullptr);
    k_agg_split<true><<<gs, 256, 0, stream>>>(t, off, csr, dinv, b3, h);
    // final FC (fp32 out, guarded)
    k_gemm<512, 256, 2, false><<<g2, 256, 0, stream>>>(h, Wtfc, d_out, bfc);
}